// Round 7
// baseline (2932.305 us; speedup 1.0000x reference)
//
#include <hip/hip_runtime.h>
#include <cstddef>

// Model constants (match reference)
#define B_  4
#define L_  4096
#define D_  512
#define H_  8
#define DH_ 64
#define F_  2048
#define M_  (B_*L_)           // 16384 rows
#define NLAYERS 4
#define EPS_LN   1e-5f
#define EPS_ATTN 1e-6f

#define EPI_NONE 0
#define EPI_RELU 1
#define EPI_PHI  2

typedef unsigned short ushort_t;
typedef short short8 __attribute__((ext_vector_type(8)));
typedef float float4v __attribute__((ext_vector_type(4)));

__device__ inline ushort_t f2bf(float f) {
    union { float f; unsigned u; } c; c.f = f;
    unsigned u = c.u;
    unsigned r = (u + 0x7fffu + ((u >> 16) & 1u)) >> 16;   // RNE
    return (ushort_t)r;
}
__device__ inline float bf2f(ushort_t h) {
    union { unsigned u; float f; } c; c.u = ((unsigned)h) << 16;
    return c.f;
}

// async global->LDS, 16B per lane; lds base must be wave-uniform
__device__ inline void async16(const ushort_t* g, ushort_t* lds) {
    __builtin_amdgcn_global_load_lds(
        (const __attribute__((address_space(1))) unsigned int*)g,
        (__attribute__((address_space(3))) unsigned int*)lds, 16, 0, 0);
}

// s_waitcnt with ONLY vmcnt constrained (lgkm=15, exp=7 free). gfx9 encoding:
// vmcnt[3:0]=bits3:0, expcnt=bits6:4, lgkmcnt=bits11:8, vmcnt[5:4]=bits15:14.
#define WAIT_VM(n) __builtin_amdgcn_s_waitcnt(0x0F70 | (n))
#define BARRIER_RAW() __builtin_amdgcn_s_barrier()

// XCD-aware swizzle: consecutive blocks go round-robin over 8 XCDs; remap so
// all column-blocks sharing one A-row-tile land on the SAME XCD (L2 reuse).
__device__ inline void swz(int& bx, int& by) {
    int gx = gridDim.x, gy = gridDim.y;
    int b = blockIdx.y * gx + blockIdx.x;
    int xcd = b & 7;
    int slot = b >> 3;
    bx = slot % gx;
    by = xcd * (gy >> 3) + slot / gx;
}

// ---------------------------------------------------------------------------
// MFMA bf16 GEMM: C[M,N] = epi(A[M,K](bf16) @ Wt[N,K]^T(bf16) + bias (+resid))
// 128x128 tile, BK=32. AITER-style pipelined K-loop: 3 LDS buffers, stages
// issued 2 tiles ahead, per-wave s_waitcnt vmcnt(4) (never 0) + raw s_barrier
// (no implicit drain). WAR-safe: barrier(it+1) orders stage(it+3) after all
// reads of buf[it%3].
// ---------------------------------------------------------------------------
__global__ __launch_bounds__(256, 2) void mfma_gemm(
    const ushort_t* __restrict__ A, const ushort_t* __restrict__ Wt,
    const float* __restrict__ bias, const float* __restrict__ resid,
    float* __restrict__ Cf, ushort_t* __restrict__ Cb,
    int N, int K, int epi)
{
    __shared__ ushort_t As[3][128 * 32];   // 3 x 8 KB
    __shared__ ushort_t Bs[3][128 * 32];   // 3 x 8 KB

    int bxi, byi;
    swz(bxi, byi);
    const int bm = byi * 128;
    const int bn = bxi * 128;
    const int tid = threadIdx.x;
    const int w = tid >> 6;
    const int lane = tid & 63;
    const int wm = w >> 1, wn = w & 1;
    const int quad = lane >> 4;
    const int m16 = lane & 15;
    const int rsub = lane >> 2;
    const int c8 = (lane & 3) * 8;

    auto stage = [&](int it) {              // 4 loads per wave
        int k0 = it << 5, bid = it % 3;
        #pragma unroll
        for (int i = 0; i < 2; ++i) {
            async16(A  + (size_t)(bm + i*64 + w*16 + rsub) * K + k0 + c8,
                    &As[bid][i*2048 + w*512]);
            async16(Wt + (size_t)(bn + i*64 + w*16 + rsub) * K + k0 + c8,
                    &Bs[bid][i*2048 + w*512]);
        }
    };

    float4v acc[4][4];
    #pragma unroll
    for (int i = 0; i < 4; ++i)
        #pragma unroll
        for (int j = 0; j < 4; ++j)
            acc[i][j] = (float4v){0.f, 0.f, 0.f, 0.f};

    auto compute = [&](int it) {
        const ushort_t* as = As[it % 3];
        const ushort_t* bs = Bs[it % 3];
        short8 af[4], bf[4];
        #pragma unroll
        for (int i = 0; i < 4; ++i) {
            af[i] = *(const short8*)&as[(wm*64 + i*16 + m16) * 32 + quad*8];
            bf[i] = *(const short8*)&bs[(wn*64 + i*16 + m16) * 32 + quad*8];
        }
        #pragma unroll
        for (int i = 0; i < 4; ++i)
            #pragma unroll
            for (int j = 0; j < 4; ++j)
                acc[i][j] = __builtin_amdgcn_mfma_f32_16x16x32_bf16(
                    af[i], bf[j], acc[i][j], 0, 0, 0);
    };

    const int nIter = K >> 5;
    stage(0);
    if (nIter > 1) stage(1);
    for (int it = 0; it < nIter - 1; ++it) {
        WAIT_VM(4);            // tile it done (tile it+1 still in flight)
        BARRIER_RAW();         // all waves' tile-it loads landed
        if (it + 2 < nIter) stage(it + 2);
        compute(it);
    }
    WAIT_VM(0);
    BARRIER_RAW();
    compute(nIter - 1);

    #pragma unroll
    for (int i = 0; i < 4; ++i) {
        #pragma unroll
        for (int j = 0; j < 4; ++j) {
            #pragma unroll
            for (int r = 0; r < 4; ++r) {
                int m = bm + wm*64 + i*16 + quad*4 + r;
                int n = bn + wn*64 + j*16 + m16;
                float v = acc[i][j][r] + bias[n];
                if (resid) v += resid[(size_t)m * N + n];
                if (epi == EPI_RELU)     v = fmaxf(v, 0.f);
                else if (epi == EPI_PHI) v = (v > 0.f) ? (v + 1.f) : __expf(v);
                if (Cf) Cf[(size_t)m * N + n] = v;
                if (Cb) Cb[(size_t)m * N + n] = f2bf(v);
            }
        }
    }
}

// ---------------------------------------------------------------------------
// (Q)/K/V projection GEMM, 128x128 tile, pipelined as above. N = nq + 1024.
// Cols [0,nq) = Q (phi, row-major), [nq,nq+512) = K (phi, -> Kt[b,h,d,s]),
// [nq+512,nq+1024) = V (none, -> Vt[b,h,d,s]).
// ---------------------------------------------------------------------------
__global__ __launch_bounds__(256, 2) void gemm_kv(
    const ushort_t* __restrict__ A, const ushort_t* __restrict__ Wt,
    const float* __restrict__ bias, int nq,
    ushort_t* __restrict__ Qb,
    ushort_t* __restrict__ Kt, ushort_t* __restrict__ Vt)
{
    const int K = 512;
    __shared__ ushort_t As[3][128 * 32];
    __shared__ ushort_t Bs[3][128 * 32];

    int bxi, byi;
    swz(bxi, byi);
    const int bm = byi * 128;
    const int bn = bxi * 128;
    const int tid = threadIdx.x;
    const int w = tid >> 6;
    const int lane = tid & 63;
    const int wm = w >> 1, wn = w & 1;
    const int quad = lane >> 4;
    const int m16 = lane & 15;
    const int rsub = lane >> 2;
    const int c8 = (lane & 3) * 8;

    auto stage = [&](int it) {
        int k0 = it << 5, bid = it % 3;
        #pragma unroll
        for (int i = 0; i < 2; ++i) {
            async16(A  + (size_t)(bm + i*64 + w*16 + rsub) * K + k0 + c8,
                    &As[bid][i*2048 + w*512]);
            async16(Wt + (size_t)(bn + i*64 + w*16 + rsub) * K + k0 + c8,
                    &Bs[bid][i*2048 + w*512]);
        }
    };

    float4v acc[4][4];
    #pragma unroll
    for (int i = 0; i < 4; ++i)
        #pragma unroll
        for (int j = 0; j < 4; ++j)
            acc[i][j] = (float4v){0.f, 0.f, 0.f, 0.f};

    auto compute = [&](int it) {
        const ushort_t* as = As[it % 3];
        const ushort_t* bs = Bs[it % 3];
        short8 af[4], bf[4];
        #pragma unroll
        for (int i = 0; i < 4; ++i) {
            af[i] = *(const short8*)&as[(wm*64 + i*16 + m16) * 32 + quad*8];
            bf[i] = *(const short8*)&bs[(wn*64 + i*16 + m16) * 32 + quad*8];
        }
        #pragma unroll
        for (int i = 0; i < 4; ++i)
            #pragma unroll
            for (int j = 0; j < 4; ++j)
                acc[i][j] = __builtin_amdgcn_mfma_f32_16x16x32_bf16(
                    af[i], bf[j], acc[i][j], 0, 0, 0);
    };

    const int nIter = K >> 5;     // 16
    stage(0); stage(1);
    for (int it = 0; it < nIter - 1; ++it) {
        WAIT_VM(4);
        BARRIER_RAW();
        if (it + 2 < nIter) stage(it + 2);
        compute(it);
    }
    WAIT_VM(0);
    BARRIER_RAW();
    compute(nIter - 1);

    #pragma unroll
    for (int i = 0; i < 4; ++i) {
        int m0 = bm + wm*64 + i*16 + quad*4;      // first of 4 rows
        int b  = m0 >> 12;
        int l  = m0 & (L_ - 1);
        #pragma unroll
        for (int j = 0; j < 4; ++j) {
            int n = bn + wn*64 + j*16 + m16;
            if (n < nq) {
                #pragma unroll
                for (int r = 0; r < 4; ++r) {
                    float v = acc[i][j][r] + bias[n];
                    v = (v > 0.f) ? (v + 1.f) : __expf(v);
                    Qb[(size_t)(m0 + r) * D_ + n] = f2bf(v);
                }
            } else {
                int nk = n - nq;
                bool isK = nk < 512;
                int nn = isK ? nk : nk - 512;
                int h = nn >> 6, dd = nn & 63;
                union { ushort_t u[4]; uint2 v2; } pk;
                #pragma unroll
                for (int r = 0; r < 4; ++r) {
                    float v = acc[i][j][r] + bias[n];
                    if (isK) v = (v > 0.f) ? (v + 1.f) : __expf(v);
                    pk.u[r] = f2bf(v);
                }
                ushort_t* dst = isK
                    ? Kt + ((size_t)(b*H_ + h) * 64 + dd) * L_ + l
                    : Vt + ((size_t)(b*H_ + h) * 64 + dd) * L_ + l;
                *(uint2*)dst = pk.v2;
            }
        }
    }
}

// ---------------------------------------------------------------------------
// kv GEMM (split-K over s, pipelined, 2 loads/wave/stage -> vmcnt(2)):
// partial kvT[sc][bh][n][d] (fp32), n<64: sum_s Vt[n][s]*Kt[d][s];
// n=64..79: ksum row via ones A-fragment. grid (32 bh, 8 s-chunks).
// ---------------------------------------------------------------------------
__global__ __launch_bounds__(256) void kv_mfma(const ushort_t* __restrict__ Kt,
                                               const ushort_t* __restrict__ Vt,
                                               float* __restrict__ kvp)
{
    __shared__ ushort_t Ks[3][64 * 32];
    __shared__ ushort_t Vs[3][64 * 32];

    const int bh = blockIdx.x;
    const int sc = blockIdx.y;
    const int CS = L_ / 8;             // 512
    const ushort_t* Kg = Kt + (size_t)bh * 64 * L_;
    const ushort_t* Vg = Vt + (size_t)bh * 64 * L_;

    const int tid = threadIdx.x;
    const int w = tid >> 6;
    const int lane = tid & 63;
    const int quad = lane >> 4;
    const int m16 = lane & 15;
    const int rsub = lane >> 2;
    const int c8 = (lane & 3) * 8;
    const int sbase = sc * CS;

    auto stage = [&](int it) {         // 2 loads per wave
        int s0 = sbase + (it << 5), bid = it % 3;
        async16(Kg + (size_t)(w*16 + rsub) * L_ + s0 + c8, &Ks[bid][w*512]);
        async16(Vg + (size_t)(w*16 + rsub) * L_ + s0 + c8, &Vs[bid][w*512]);
    };

    // constant ones-fragment: A[m][k] = (m==0) ? 1.0 : 0  ->  row 64 = ksum
    short8 onesfrag;
    {
        ushort_t v = (m16 == 0) ? (ushort_t)0x3F80 : (ushort_t)0;
        #pragma unroll
        for (int j = 0; j < 8; ++j) onesfrag[j] = (short)v;
    }

    float4v acc[5];
    #pragma unroll
    for (int i = 0; i < 5; ++i) acc[i] = (float4v){0.f, 0.f, 0.f, 0.f};

    auto compute = [&](int it) {
        const ushort_t* ks = Ks[it % 3];
        const ushort_t* vs = Vs[it % 3];
        short8 bfrag = *(const short8*)&ks[(w*16 + m16) * 32 + quad*8];
        #pragma unroll
        for (int nt = 0; nt < 4; ++nt) {
            short8 afrag = *(const short8*)&vs[(nt*16 + m16) * 32 + quad*8];
            acc[nt] = __builtin_amdgcn_mfma_f32_16x16x32_bf16(
                afrag, bfrag, acc[nt], 0, 0, 0);
        }
        acc[4] = __builtin_amdgcn_mfma_f32_16x16x32_bf16(
            onesfrag, bfrag, acc[4], 0, 0, 0);
    };

    const int nIter = CS >> 5;        // 16
    stage(0); stage(1);
    for (int it = 0; it < nIter - 1; ++it) {
        WAIT_VM(2);
        BARRIER_RAW();
        if (it + 2 < nIter) stage(it + 2);
        compute(it);
    }
    WAIT_VM(0);
    BARRIER_RAW();
    compute(nIter - 1);

    float* dst = kvp + ((size_t)sc * 32 + bh) * 80 * 64;
    #pragma unroll
    for (int nt = 0; nt < 5; ++nt)
        #pragma unroll
        for (int r = 0; r < 4; ++r) {
            int n = nt*16 + quad*4 + r;
            int d = w*16 + m16;
            dst[n * 64 + d] = acc[nt][r];
        }
}

// reduce 8 fp32 partials -> bf16 kvb[32][80][64]
__global__ void kv_reduce(const float* __restrict__ kvp, ushort_t* __restrict__ kvb)
{
    int i = blockIdx.x * 256 + threadIdx.x;    // < 32*80*64
    float s = 0.f;
    #pragma unroll
    for (int sc = 0; sc < 8; ++sc)
        s += kvp[(size_t)sc * 32 * 80 * 64 + i];
    kvb[i] = f2bf(s);
}

// ---------------------------------------------------------------------------
// attn out: O[l][0..79] = Q[l,:] @ kvT^T ; col 64 = z; write cols 0..63 / (z+eps)
// grid (32 bh, 32 l-tiles); 128 l x 80 n per block; K=64 (2 k-steps).
// ---------------------------------------------------------------------------
__global__ __launch_bounds__(256) void attn_out_mfma(const ushort_t* __restrict__ Q,
                                                     const ushort_t* __restrict__ kvb,
                                                     ushort_t* __restrict__ ab)
{
    __shared__ ushort_t Qs[128 * 64];  // 16KB
    __shared__ float zbuf[128];

    const int bh = blockIdx.x;
    const int h = bh & 7, b = bh >> 3;
    const int l0 = blockIdx.y * 128;

    const int tid = threadIdx.x;
    const int w = tid >> 6;
    const int lane = tid & 63;
    const int quad = lane >> 4;
    const int m16 = lane & 15;

    // b-frags straight from global (L2-resident, 10KB reused by 32 blocks/bh)
    const ushort_t* kv = kvb + (size_t)bh * 80 * 64;
    short8 bf[5][2];
    #pragma unroll
    for (int j = 0; j < 5; ++j)
        #pragma unroll
        for (int t = 0; t < 2; ++t)
            bf[j][t] = *(const short8*)(kv + (j*16 + m16) * 64 + t*32 + quad*8);

    // stage Q rows l0..l0+127, k=0..63
    #pragma unroll
    for (int i = 0; i < 4; ++i)
        async16(Q + (size_t)(b*L_ + l0 + i*32 + w*8 + (lane >> 3)) * D_
                  + h*64 + (lane & 7)*8,
                &Qs[(i*32 + w*8) * 64]);
    __syncthreads();

    float4v acc[2][5];
    #pragma unroll
    for (int i = 0; i < 2; ++i)
        #pragma unroll
        for (int j = 0; j < 5; ++j)
            acc[i][j] = (float4v){0.f, 0.f, 0.f, 0.f};

    #pragma unroll
    for (int t = 0; t < 2; ++t) {
        short8 af[2];
        #pragma unroll
        for (int i = 0; i < 2; ++i)
            af[i] = *(const short8*)&Qs[(w*32 + i*16 + m16) * 64 + t*32 + quad*8];
        #pragma unroll
        for (int i = 0; i < 2; ++i)
            #pragma unroll
            for (int j = 0; j < 5; ++j)
                acc[i][j] = __builtin_amdgcn_mfma_f32_16x16x32_bf16(
                    af[i], bf[j][t], acc[i][j], 0, 0, 0);
    }

    // z lives in n=64 -> tile j=4, lanes m16==0
    if (m16 == 0) {
        #pragma unroll
        for (int i = 0; i < 2; ++i)
            #pragma unroll
            for (int r = 0; r < 4; ++r)
                zbuf[w*32 + i*16 + quad*4 + r] = acc[i][4][r];
    }
    __syncthreads();

    #pragma unroll
    for (int i = 0; i < 2; ++i) {
        #pragma unroll
        for (int r = 0; r < 4; ++r) {
            int lrow = w*32 + i*16 + quad*4 + r;
            float zin = 1.f / (zbuf[lrow] + EPS_ATTN);
            #pragma unroll
            for (int j = 0; j < 4; ++j) {
                ab[(size_t)(b*L_ + l0 + lrow) * D_ + h*64 + j*16 + m16]
                    = f2bf(acc[i][j][r] * zin);
            }
        }
    }
}

// ---------------------------------------------------------------------------
// Weight transpose+convert: src[K,N] fp32 -> dst[N,K] bf16. blockIdx.z = matrix.
// ---------------------------------------------------------------------------
__global__ __launch_bounds__(256) void wconv_kernel(const float* __restrict__ src,
                                                    ushort_t* __restrict__ dst,
                                                    int K, int N)
{
    __shared__ float tile[32][33];
    size_t moff = (size_t)blockIdx.z * K * N;
    src += moff; dst += moff;
    int n0 = blockIdx.x * 32, k0 = blockIdx.y * 32;
    int tx = threadIdx.x & 31, ty = threadIdx.x >> 5;
    #pragma unroll
    for (int i = 0; i < 4; ++i)
        tile[ty + i*8][tx] = src[(size_t)(k0 + ty + i*8) * N + n0 + tx];
    __syncthreads();
    #pragma unroll
    for (int i = 0; i < 4; ++i)
        dst[(size_t)(n0 + ty + i*8) * K + k0 + tx] = f2bf(tile[tx][ty + i*8]);
}

// ---------------------------------------------------------------------------
// Embedding / broadcast / LN / pred
// ---------------------------------------------------------------------------
__global__ void embed_kernel(const float* __restrict__ x, const float* __restrict__ pe,
                             const float* __restrict__ ew, const float* __restrict__ eb,
                             float* __restrict__ hf, ushort_t* __restrict__ hb)
{
    size_t row = blockIdx.x;
    int c = threadIdx.x;
    int l = (int)(row % L_);
    float x0 = x[row*2], x1 = x[row*2+1];
    float v0 = fmaf(x0, ew[c], fmaf(x1, ew[256 + c], eb[c]));
    float v1 = pe[(size_t)l*256 + c];
    hf[row*(size_t)D_ + c]       = v0;
    hf[row*(size_t)D_ + 256 + c] = v1;
    hb[row*(size_t)D_ + c]       = f2bf(v0);
    hb[row*(size_t)D_ + 256 + c] = f2bf(v1);
}

__global__ void bcast_kernel(const float* __restrict__ src,
                             float* __restrict__ dstf, ushort_t* __restrict__ dstb)
{
    size_t i = (size_t)blockIdx.x * 256 + threadIdx.x;
    float v = src[i];
    ushort_t bb16 = f2bf(v);
    #pragma unroll
    for (int bb = 0; bb < B_; ++bb) {
        dstf[(size_t)bb * L_ * D_ + i] = v;
        dstb[(size_t)bb * L_ * D_ + i] = bb16;
    }
}

__global__ __launch_bounds__(256) void ln_kernel(const float* __restrict__ X,
                                                 const float* __restrict__ gb,
                                                 float* __restrict__ Yf,
                                                 ushort_t* __restrict__ Yb)
{
    int row = blockIdx.x * 4 + (threadIdx.x >> 6);
    int lane = threadIdx.x & 63;
    const float* x = X + (size_t)row * D_;
    float v[8];
    float s = 0.f;
    #pragma unroll
    for (int i = 0; i < 8; ++i) { v[i] = x[lane + i*64]; s += v[i]; }
    #pragma unroll
    for (int off = 32; off >= 1; off >>= 1) s += __shfl_xor(s, off, 64);
    float mu = s * (1.f / D_);
    float sq = 0.f;
    #pragma unroll
    for (int i = 0; i < 8; ++i) { float d = v[i] - mu; sq += d * d; }
    #pragma unroll
    for (int off = 32; off >= 1; off >>= 1) sq += __shfl_xor(sq, off, 64);
    float rstd = rsqrtf(sq * (1.f / D_) + EPS_LN);
    #pragma unroll
    for (int i = 0; i < 8; ++i) {
        int c = lane + i*64;
        float y = (v[i] - mu) * rstd * gb[c] + gb[512 + c];
        Yf[(size_t)row * D_ + c] = y;
        if (Yb) Yb[(size_t)row * D_ + c] = f2bf(y);
    }
}

__global__ __launch_bounds__(256) void pred_kernel(const float* __restrict__ X,
                                                   const float* __restrict__ pw,
                                                   const float* __restrict__ pb,
                                                   float* __restrict__ out)
{
    int row = blockIdx.x * 4 + (threadIdx.x >> 6);
    int lane = threadIdx.x & 63;
    const float* x = X + (size_t)row * D_;
    float a0 = 0.f, a1 = 0.f;
    #pragma unroll
    for (int i = 0; i < 8; ++i) {
        int c = lane + i*64;
        float v = x[c];
        a0 = fmaf(v, pw[c*2 + 0], a0);
        a1 = fmaf(v, pw[c*2 + 1], a1);
    }
    #pragma unroll
    for (int off = 32; off >= 1; off >>= 1) {
        a0 += __shfl_xor(a0, off, 64);
        a1 += __shfl_xor(a1, off, 64);
    }
    if (lane == 0) {
        out[(size_t)row*2 + 0] = a0 + pb[0];
        out[(size_t)row*2 + 1] = a1 + pb[1];
    }
}

// ---------------------------------------------------------------------------
// Host-side orchestration
// ---------------------------------------------------------------------------
extern "C" void kernel_launch(void* const* d_in, const int* in_sizes, int n_in,
                              void* d_out, int out_size, void* d_ws, size_t ws_size,
                              hipStream_t stream)
{
    const float* x            = (const float*)d_in[0];
    const float* out_pos_emb  = (const float*)d_in[1];
    const float* pe_input     = (const float*)d_in[2];
    const float* emb_w        = (const float*)d_in[3];
    const float* emb_b        = (const float*)d_in[4];
    const float* enc_attn_w   = (const float*)d_in[5];
    const float* enc_attn_b   = (const float*)d_in[6];
    const float* enc_ln       = (const float*)d_in[7];
    const float* enc_ff_w1    = (const float*)d_in[8];
    const float* enc_ff_b1    = (const float*)d_in[9];
    const float* enc_ff_w2    = (const float*)d_in[10];
    const float* enc_ff_b2    = (const float*)d_in[11];
    const float* enc_final_ln = (const float*)d_in[12];
    const float* dec_self_w   = (const float*)d_in[13];
    const float* dec_self_b   = (const float*)d_in[14];
    const float* dec_cross_w  = (const float*)d_in[15];
    const float* dec_cross_b  = (const float*)d_in[16];
    const float* dec_ln       = (const float*)d_in[17];
    const float* dec_ff_w1    = (const float*)d_in[18];
    const float* dec_ff_b1    = (const float*)d_in[19];
    const float* dec_ff_w2    = (const float*)d_in[20];
    const float* dec_ff_b2    = (const float*)d_in[21];
    const float* dec_final_ln = (const float*)d_in[22];
    const float* pred_w       = (const float*)d_in[23];
    const float* pred_b       = (const float*)d_in[24];
    float* out = (float*)d_out;

    // ---- workspace layout (~198 MB) ----
    const size_t MD = (size_t)M_ * D_;            // 8.39M
    float*    h_f32 = (float*)d_ws;               // MD f32 (residual state, in-place)
    ushort_t* h_b   = (ushort_t*)(h_f32 + MD);    // MD bf16
    ushort_t* z_b   = h_b + MD;                   // MD bf16
    ushort_t* un    = z_b + MD;                   // union region
    // attn view of union:
    ushort_t* Qb = un;                            // MD
    ushort_t* ab = un + MD;                       // MD
    ushort_t* Kt = un + 2*MD;                     // 32*64*4096 = MD
    ushort_t* Vt = un + 3*MD;                     // 32*64*4096 = MD
    // ffn view of union:
    ushort_t* ffh = un;                           // M*F = 4*MD
    const size_t UN_ELEMS = 4*MD;
    ushort_t* kvb = un + UN_ELEMS;                // 32*80*64 bf16
    float*    kvp = (float*)(kvb + (size_t)32*80*64);   // 8*32*80*64 fp32 (5.2MB)
    ushort_t* wts = (ushort_t*)(kvp + (size_t)8*32*80*64);

    const size_t ATT_MAT = (size_t)D_ * D_;
    const size_t ATT_LYR = 4 * ATT_MAT;
    const size_t FF_MAT  = (size_t)D_ * F_;
    ushort_t* wt_enc_att   = wts;
    ushort_t* wt_dec_self  = wt_enc_att  + 4 * ATT_LYR;
    ushort_t* wt_dec_cross = wt_dec_self + 4 * ATT_LYR;
    ushort_t* wt_enc_ff1   = wt_dec_cross + 4 * ATT_LYR;
    ushort_t* wt_enc_ff2   = wt_enc_ff1  + 4 * FF_MAT;
    ushort_t* wt_dec_ff1   = wt_enc_ff2  + 4 * FF_MAT;
    ushort_t* wt_dec_ff2   = wt_dec_ff1  + 4 * FF_MAT;

    // ---- weight conversion (fp32 [K,N] -> bf16 [N,K]) ----
    hipLaunchKernelGGL(wconv_kernel, dim3(16, 16, 16), dim3(256), 0, stream,
                       enc_attn_w, wt_enc_att, D_, D_);
    hipLaunchKernelGGL(wconv_kernel, dim3(16, 16, 16), dim3(256), 0, stream,
                       dec_self_w, wt_dec_self, D_, D_);
    hipLaunchKernelGGL(wconv_kernel, dim3(16, 16, 16), dim3(256), 0, stream,
                       dec_cross_w, wt_dec_cross, D_, D_);
    hipLaunchKernelGGL(wconv_kernel, dim3(64, 16, 4), dim3(256), 0, stream,
                       enc_ff_w1, wt_enc_ff1, D_, F_);
    hipLaunchKernelGGL(wconv_kernel, dim3(16, 64, 4), dim3(256), 0, stream,
                       enc_ff_w2, wt_enc_ff2, F_, D_);
    hipLaunchKernelGGL(wconv_kernel, dim3(64, 16, 4), dim3(256), 0, stream,
                       dec_ff_w1, wt_dec_ff1, D_, F_);
    hipLaunchKernelGGL(wconv_kernel, dim3(16, 64, 4), dim3(256), 0, stream,
                       dec_ff_w2, wt_dec_ff2, F_, D_);

    auto gemm = [&](const ushort_t* A, const ushort_t* Wt, const float* bias,
                    const float* resid, float* Cf, ushort_t* Cb, int N, int K, int epi) {
        dim3 grid(N / 128, M_ / 128);
        hipLaunchKernelGGL(mfma_gemm, grid, dim3(256), 0, stream,
                           A, Wt, bias, resid, Cf, Cb, N, K, epi);
    };
    auto layernorm = [&](const float* gb, ushort_t* Yb) {   // in-place on h_f32
        hipLaunchKernelGGL(ln_kernel, dim3(M_ / 4), dim3(256), 0, stream,
                           h_f32, gb, h_f32, Yb);
    };
    // attention: h_f32 += proj(linear_attn(phi(xq Wq), phi(xkv Wk), xkv Wv))
    auto attn = [&](const ushort_t* xq_b, const ushort_t* xkv_b, bool self,
                    const ushort_t* wt, const float* bv) {
        if (self) {
            // fused Q|K|V projection, N = 1536
            hipLaunchKernelGGL(gemm_kv, dim3(12, 128), dim3(256), 0, stream,
                               xkv_b, wt, bv, 512, Qb, Kt, Vt);
        } else {
            gemm(xq_b, wt, bv, nullptr, nullptr, Qb, D_, D_, EPI_PHI);
            hipLaunchKernelGGL(gemm_kv, dim3(8, 128), dim3(256), 0, stream,
                               xkv_b, wt + ATT_MAT, bv + D_, 0, nullptr, Kt, Vt);
        }
        hipLaunchKernelGGL(kv_mfma, dim3(32, 8), dim3(256), 0, stream, Kt, Vt, kvp);
        hipLaunchKernelGGL(kv_reduce, dim3(32*80*64/256), dim3(256), 0, stream,
                           kvp, kvb);
        hipLaunchKernelGGL(attn_out_mfma, dim3(32, 32), dim3(256), 0, stream,
                           Qb, kvb, ab);
        gemm(ab, wt + 3*ATT_MAT, bv + 3*D_, h_f32, h_f32, nullptr, D_, D_, EPI_NONE);
    };
    auto ffn = [&](const ushort_t* wt1, const float* b1,
                   const ushort_t* wt2, const float* b2) {
        gemm(h_b, wt1, b1, nullptr, nullptr, ffh, F_, D_, EPI_RELU);
        gemm(ffh, wt2, b2, h_f32, h_f32, nullptr, D_, F_, EPI_NONE);
    };

    // ---- embedding ----
    hipLaunchKernelGGL(embed_kernel, dim3(M_), dim3(256), 0, stream,
                       x, pe_input, emb_w, emb_b, h_f32, h_b);

    // ---- encoder ----
    for (int l = 0; l < NLAYERS; ++l) {
        attn(h_b, h_b, true, wt_enc_att + l * ATT_LYR, enc_attn_b + (size_t)l * 4 * D_);
        layernorm(enc_ln + (size_t)(l*2 + 0) * 2 * D_, h_b);
        ffn(wt_enc_ff1 + l * FF_MAT, enc_ff_b1 + (size_t)l * F_,
            wt_enc_ff2 + l * FF_MAT, enc_ff_b2 + (size_t)l * D_);
        layernorm(enc_ln + (size_t)(l*2 + 1) * 2 * D_, h_b);
    }
    layernorm(enc_final_ln, z_b);    // z (bf16) = encoder memory

    // ---- decoder ----
    hipLaunchKernelGGL(bcast_kernel, dim3(L_ * D_ / 256), dim3(256), 0, stream,
                       out_pos_emb, h_f32, h_b);
    for (int l = 0; l < NLAYERS; ++l) {
        attn(h_b, h_b, true, wt_dec_self + l * ATT_LYR, dec_self_b + (size_t)l * 4 * D_);
        layernorm(dec_ln + (size_t)(l*3 + 0) * 2 * D_, h_b);
        attn(h_b, z_b, false, wt_dec_cross + l * ATT_LYR, dec_cross_b + (size_t)l * 4 * D_);
        layernorm(dec_ln + (size_t)(l*3 + 1) * 2 * D_, h_b);
        ffn(wt_dec_ff1 + l * FF_MAT, dec_ff_b1 + (size_t)l * F_,
            wt_dec_ff2 + l * FF_MAT, dec_ff_b2 + (size_t)l * D_);
        layernorm(dec_ln + (size_t)(l*3 + 2) * 2 * D_, h_b);
    }
    layernorm(dec_final_ln, nullptr);   // in-place on h_f32

    // ---- prediction head ----
    hipLaunchKernelGGL(pred_kernel, dim3(M_ / 4), dim3(256), 0, stream,
                       h_f32, pred_w, pred_b, out);
}

// Round 8
// 2594.834 us; speedup vs baseline: 1.1301x; 1.1301x over previous
//
#include <hip/hip_runtime.h>
#include <cstddef>

// Model constants (match reference)
#define B_  4
#define L_  4096
#define D_  512
#define H_  8
#define DH_ 64
#define F_  2048
#define M_  (B_*L_)           // 16384 rows
#define NLAYERS 4
#define EPS_LN   1e-5f
#define EPS_ATTN 1e-6f

#define EPI_NONE 0
#define EPI_RELU 1
#define EPI_PHI  2

typedef unsigned short ushort_t;
typedef short short8 __attribute__((ext_vector_type(8)));
typedef float float4v __attribute__((ext_vector_type(4)));

__device__ inline ushort_t f2bf(float f) {
    union { float f; unsigned u; } c; c.f = f;
    unsigned u = c.u;
    unsigned r = (u + 0x7fffu + ((u >> 16) & 1u)) >> 16;   // RNE
    return (ushort_t)r;
}
__device__ inline float bf2f(ushort_t h) {
    union { unsigned u; float f; } c; c.u = ((unsigned)h) << 16;
    return c.f;
}

// async global->LDS, 16B per lane; lds base must be wave-uniform
__device__ inline void async16(const ushort_t* g, ushort_t* lds) {
    __builtin_amdgcn_global_load_lds(
        (const __attribute__((address_space(1))) unsigned int*)g,
        (__attribute__((address_space(3))) unsigned int*)lds, 16, 0, 0);
}

// XCD-aware swizzle: consecutive blocks go round-robin over 8 XCDs; remap so
// all column-blocks sharing one A-row-tile land on the SAME XCD (L2 reuse).
__device__ inline void swz(int& bx, int& by) {
    int gx = gridDim.x, gy = gridDim.y;
    int b = blockIdx.y * gx + blockIdx.x;
    int xcd = b & 7;
    int slot = b >> 3;
    bx = slot % gx;
    by = xcd * (gy >> 3) + slot / gx;
}

// ---------------------------------------------------------------------------
// MFMA bf16 GEMM: C[M,N] = epi(A[M,K](bf16) @ Wt[N,K]^T(bf16) + bias (+resid))
// 128x128 tile, BK=32, 512 threads = 8 waves (4x2), each wave 32x64
// (acc[2][4], 32 AGPRs). Double-buffered LDS; 1 A + 1 B async16 per wave
// per stage. 16 waves/CU at 2 blocks/CU -> 2x the in-flight loads vs 4-wave.
// ---------------------------------------------------------------------------
__global__ __launch_bounds__(512, 2) void mfma_gemm(
    const ushort_t* __restrict__ A, const ushort_t* __restrict__ Wt,
    const float* __restrict__ bias, const float* __restrict__ resid,
    float* __restrict__ Cf, ushort_t* __restrict__ Cb,
    int N, int K, int epi)
{
    __shared__ ushort_t As[2][128 * 32];   // 2 x 8 KB
    __shared__ ushort_t Bs[2][128 * 32];   // 2 x 8 KB

    int bxi, byi;
    swz(bxi, byi);
    const int bm = byi * 128;
    const int bn = bxi * 128;
    const int tid = threadIdx.x;
    const int w = tid >> 6;          // wave 0..7
    const int lane = tid & 63;
    const int wm = w >> 1;           // 0..3 (32-row strip)
    const int wn = w & 1;            // 0..1 (64-col strip)
    const int quad = lane >> 4;
    const int m16 = lane & 15;
    const int rsub = lane >> 2;      // 0..15
    const int c8 = (lane & 3) * 8;

    auto stage = [&](int k0, int bid) {     // 2 loads per wave
        async16(A  + (size_t)(bm + w*16 + rsub) * K + k0 + c8, &As[bid][w*512]);
        async16(Wt + (size_t)(bn + w*16 + rsub) * K + k0 + c8, &Bs[bid][w*512]);
    };

    float4v acc[2][4];
    #pragma unroll
    for (int i = 0; i < 2; ++i)
        #pragma unroll
        for (int j = 0; j < 4; ++j)
            acc[i][j] = (float4v){0.f, 0.f, 0.f, 0.f};

    auto compute = [&](int bid) {
        const ushort_t* as = As[bid];
        const ushort_t* bs = Bs[bid];
        short8 af[2], bf[4];
        #pragma unroll
        for (int i = 0; i < 2; ++i)
            af[i] = *(const short8*)&as[(wm*32 + i*16 + m16) * 32 + quad*8];
        #pragma unroll
        for (int j = 0; j < 4; ++j)
            bf[j] = *(const short8*)&bs[(wn*64 + j*16 + m16) * 32 + quad*8];
        #pragma unroll
        for (int i = 0; i < 2; ++i)
            #pragma unroll
            for (int j = 0; j < 4; ++j)
                acc[i][j] = __builtin_amdgcn_mfma_f32_16x16x32_bf16(
                    af[i], bf[j], acc[i][j], 0, 0, 0);
    };

    const int nIter = K >> 5;
    stage(0, 0);
    for (int it = 0; it < nIter; ++it) {
        __syncthreads();                    // drain tile-it loads
        if (it + 1 < nIter) stage((it + 1) << 5, (it + 1) & 1);
        compute(it & 1);
    }

    #pragma unroll
    for (int i = 0; i < 2; ++i) {
        #pragma unroll
        for (int j = 0; j < 4; ++j) {
            #pragma unroll
            for (int r = 0; r < 4; ++r) {
                int m = bm + wm*32 + i*16 + quad*4 + r;
                int n = bn + wn*64 + j*16 + m16;
                float v = acc[i][j][r] + bias[n];
                if (resid) v += resid[(size_t)m * N + n];
                if (epi == EPI_RELU)     v = fmaxf(v, 0.f);
                else if (epi == EPI_PHI) v = (v > 0.f) ? (v + 1.f) : __expf(v);
                if (Cf) Cf[(size_t)m * N + n] = v;
                if (Cb) Cb[(size_t)m * N + n] = f2bf(v);
            }
        }
    }
}

// ---------------------------------------------------------------------------
// (Q)/K/V projection GEMM, 128x128 tile, 512 threads, dbuf. N = nq + 1024.
// Cols [0,nq) = Q (phi, row-major), [nq,nq+512) = K (phi, -> Kt[b,h,d,s]),
// [nq+512,nq+1024) = V (none, -> Vt[b,h,d,s]).
// ---------------------------------------------------------------------------
__global__ __launch_bounds__(512, 2) void gemm_kv(
    const ushort_t* __restrict__ A, const ushort_t* __restrict__ Wt,
    const float* __restrict__ bias, int nq,
    ushort_t* __restrict__ Qb,
    ushort_t* __restrict__ Kt, ushort_t* __restrict__ Vt)
{
    const int K = 512;
    __shared__ ushort_t As[2][128 * 32];
    __shared__ ushort_t Bs[2][128 * 32];

    int bxi, byi;
    swz(bxi, byi);
    const int bm = byi * 128;
    const int bn = bxi * 128;
    const int tid = threadIdx.x;
    const int w = tid >> 6;
    const int lane = tid & 63;
    const int wm = w >> 1, wn = w & 1;
    const int quad = lane >> 4;
    const int m16 = lane & 15;
    const int rsub = lane >> 2;
    const int c8 = (lane & 3) * 8;

    auto stage = [&](int k0, int bid) {
        async16(A  + (size_t)(bm + w*16 + rsub) * K + k0 + c8, &As[bid][w*512]);
        async16(Wt + (size_t)(bn + w*16 + rsub) * K + k0 + c8, &Bs[bid][w*512]);
    };

    float4v acc[2][4];
    #pragma unroll
    for (int i = 0; i < 2; ++i)
        #pragma unroll
        for (int j = 0; j < 4; ++j)
            acc[i][j] = (float4v){0.f, 0.f, 0.f, 0.f};

    auto compute = [&](int bid) {
        const ushort_t* as = As[bid];
        const ushort_t* bs = Bs[bid];
        short8 af[2], bf[4];
        #pragma unroll
        for (int i = 0; i < 2; ++i)
            af[i] = *(const short8*)&as[(wm*32 + i*16 + m16) * 32 + quad*8];
        #pragma unroll
        for (int j = 0; j < 4; ++j)
            bf[j] = *(const short8*)&bs[(wn*64 + j*16 + m16) * 32 + quad*8];
        #pragma unroll
        for (int i = 0; i < 2; ++i)
            #pragma unroll
            for (int j = 0; j < 4; ++j)
                acc[i][j] = __builtin_amdgcn_mfma_f32_16x16x32_bf16(
                    af[i], bf[j], acc[i][j], 0, 0, 0);
    };

    const int nIter = K >> 5;     // 16
    stage(0, 0);
    for (int it = 0; it < nIter; ++it) {
        __syncthreads();
        if (it + 1 < nIter) stage((it + 1) << 5, (it + 1) & 1);
        compute(it & 1);
    }

    #pragma unroll
    for (int i = 0; i < 2; ++i) {
        int m0 = bm + wm*32 + i*16 + quad*4;      // first of 4 rows
        int b  = m0 >> 12;
        int l  = m0 & (L_ - 1);
        #pragma unroll
        for (int j = 0; j < 4; ++j) {
            int n = bn + wn*64 + j*16 + m16;
            if (n < nq) {
                #pragma unroll
                for (int r = 0; r < 4; ++r) {
                    float v = acc[i][j][r] + bias[n];
                    v = (v > 0.f) ? (v + 1.f) : __expf(v);
                    Qb[(size_t)(m0 + r) * D_ + n] = f2bf(v);
                }
            } else {
                int nk = n - nq;
                bool isK = nk < 512;
                int nn = isK ? nk : nk - 512;
                int h = nn >> 6, dd = nn & 63;
                union { ushort_t u[4]; uint2 v2; } pk;
                #pragma unroll
                for (int r = 0; r < 4; ++r) {
                    float v = acc[i][j][r] + bias[n];
                    if (isK) v = (v > 0.f) ? (v + 1.f) : __expf(v);
                    pk.u[r] = f2bf(v);
                }
                ushort_t* dst = isK
                    ? Kt + ((size_t)(b*H_ + h) * 64 + dd) * L_ + l
                    : Vt + ((size_t)(b*H_ + h) * 64 + dd) * L_ + l;
                *(uint2*)dst = pk.v2;
            }
        }
    }
}

// ---------------------------------------------------------------------------
// kv GEMM (split-K over s, dbuf): partial kvT[sc][bh][n][d] (fp32),
// n<64: sum_s Vt[n][s]*Kt[d][s]; n=64..79: ksum row via ones A-fragment.
// grid (32 bh, 8 s-chunks); wave w owns d-tile w, all 5 n-tiles.
// ---------------------------------------------------------------------------
__global__ __launch_bounds__(256) void kv_mfma(const ushort_t* __restrict__ Kt,
                                               const ushort_t* __restrict__ Vt,
                                               float* __restrict__ kvp)
{
    __shared__ ushort_t Ks[2][64 * 32];
    __shared__ ushort_t Vs[2][64 * 32];

    const int bh = blockIdx.x;
    const int sc = blockIdx.y;
    const int CS = L_ / 8;             // 512
    const ushort_t* Kg = Kt + (size_t)bh * 64 * L_;
    const ushort_t* Vg = Vt + (size_t)bh * 64 * L_;

    const int tid = threadIdx.x;
    const int w = tid >> 6;
    const int lane = tid & 63;
    const int quad = lane >> 4;
    const int m16 = lane & 15;
    const int rsub = lane >> 2;
    const int c8 = (lane & 3) * 8;
    const int sbase = sc * CS;

    auto stage = [&](int s0, int bid) {
        async16(Kg + (size_t)(w*16 + rsub) * L_ + s0 + c8, &Ks[bid][w*512]);
        async16(Vg + (size_t)(w*16 + rsub) * L_ + s0 + c8, &Vs[bid][w*512]);
    };

    // constant ones-fragment: A[m][k] = (m==0) ? 1.0 : 0  ->  row 64 = ksum
    short8 onesfrag;
    {
        ushort_t v = (m16 == 0) ? (ushort_t)0x3F80 : (ushort_t)0;
        #pragma unroll
        for (int j = 0; j < 8; ++j) onesfrag[j] = (short)v;
    }

    float4v acc[5];
    #pragma unroll
    for (int i = 0; i < 5; ++i) acc[i] = (float4v){0.f, 0.f, 0.f, 0.f};

    const int nIter = CS >> 5;        // 16
    stage(sbase, 0);
    for (int it = 0; it < nIter; ++it) {
        __syncthreads();
        if (it + 1 < nIter) stage(sbase + ((it + 1) << 5), (it + 1) & 1);
        const ushort_t* ks = Ks[it & 1];
        const ushort_t* vs = Vs[it & 1];

        short8 bfrag = *(const short8*)&ks[(w*16 + m16) * 32 + quad*8];
        #pragma unroll
        for (int nt = 0; nt < 4; ++nt) {
            short8 afrag = *(const short8*)&vs[(nt*16 + m16) * 32 + quad*8];
            acc[nt] = __builtin_amdgcn_mfma_f32_16x16x32_bf16(
                afrag, bfrag, acc[nt], 0, 0, 0);
        }
        acc[4] = __builtin_amdgcn_mfma_f32_16x16x32_bf16(
            onesfrag, bfrag, acc[4], 0, 0, 0);
    }

    float* dst = kvp + ((size_t)sc * 32 + bh) * 80 * 64;
    #pragma unroll
    for (int nt = 0; nt < 5; ++nt)
        #pragma unroll
        for (int r = 0; r < 4; ++r) {
            int n = nt*16 + quad*4 + r;
            int d = w*16 + m16;
            dst[n * 64 + d] = acc[nt][r];
        }
}

// reduce 8 fp32 partials -> bf16 kvb[32][80][64]
__global__ void kv_reduce(const float* __restrict__ kvp, ushort_t* __restrict__ kvb)
{
    int i = blockIdx.x * 256 + threadIdx.x;    // < 32*80*64
    float s = 0.f;
    #pragma unroll
    for (int sc = 0; sc < 8; ++sc)
        s += kvp[(size_t)sc * 32 * 80 * 64 + i];
    kvb[i] = f2bf(s);
}

// ---------------------------------------------------------------------------
// attn out: O[l][0..79] = Q[l,:] @ kvT^T ; col 64 = z; write cols 0..63 / (z+eps)
// grid (32 bh, 32 l-tiles); 128 l x 80 n per block; K=64 (2 k-steps).
// ---------------------------------------------------------------------------
__global__ __launch_bounds__(256) void attn_out_mfma(const ushort_t* __restrict__ Q,
                                                     const ushort_t* __restrict__ kvb,
                                                     ushort_t* __restrict__ ab)
{
    __shared__ ushort_t Qs[128 * 64];  // 16KB
    __shared__ float zbuf[128];

    const int bh = blockIdx.x;
    const int h = bh & 7, b = bh >> 3;
    const int l0 = blockIdx.y * 128;

    const int tid = threadIdx.x;
    const int w = tid >> 6;
    const int lane = tid & 63;
    const int quad = lane >> 4;
    const int m16 = lane & 15;

    // b-frags straight from global (L2-resident, 10KB reused by 32 blocks/bh)
    const ushort_t* kv = kvb + (size_t)bh * 80 * 64;
    short8 bf[5][2];
    #pragma unroll
    for (int j = 0; j < 5; ++j)
        #pragma unroll
        for (int t = 0; t < 2; ++t)
            bf[j][t] = *(const short8*)(kv + (j*16 + m16) * 64 + t*32 + quad*8);

    // stage Q rows l0..l0+127, k=0..63
    #pragma unroll
    for (int i = 0; i < 4; ++i)
        async16(Q + (size_t)(b*L_ + l0 + i*32 + w*8 + (lane >> 3)) * D_
                  + h*64 + (lane & 7)*8,
                &Qs[(i*32 + w*8) * 64]);
    __syncthreads();

    float4v acc[2][5];
    #pragma unroll
    for (int i = 0; i < 2; ++i)
        #pragma unroll
        for (int j = 0; j < 5; ++j)
            acc[i][j] = (float4v){0.f, 0.f, 0.f, 0.f};

    #pragma unroll
    for (int t = 0; t < 2; ++t) {
        short8 af[2];
        #pragma unroll
        for (int i = 0; i < 2; ++i)
            af[i] = *(const short8*)&Qs[(w*32 + i*16 + m16) * 64 + t*32 + quad*8];
        #pragma unroll
        for (int i = 0; i < 2; ++i)
            #pragma unroll
            for (int j = 0; j < 5; ++j)
                acc[i][j] = __builtin_amdgcn_mfma_f32_16x16x32_bf16(
                    af[i], bf[j][t], acc[i][j], 0, 0, 0);
    }

    // z lives in n=64 -> tile j=4, lanes m16==0
    if (m16 == 0) {
        #pragma unroll
        for (int i = 0; i < 2; ++i)
            #pragma unroll
            for (int r = 0; r < 4; ++r)
                zbuf[w*32 + i*16 + quad*4 + r] = acc[i][4][r];
    }
    __syncthreads();

    #pragma unroll
    for (int i = 0; i < 2; ++i) {
        #pragma unroll
        for (int r = 0; r < 4; ++r) {
            int lrow = w*32 + i*16 + quad*4 + r;
            float zin = 1.f / (zbuf[lrow] + EPS_ATTN);
            #pragma unroll
            for (int j = 0; j < 4; ++j) {
                ab[(size_t)(b*L_ + l0 + lrow) * D_ + h*64 + j*16 + m16]
                    = f2bf(acc[i][j][r] * zin);
            }
        }
    }
}

// ---------------------------------------------------------------------------
// Weight transpose+convert: src[K,N] fp32 -> dst[N,K] bf16. blockIdx.z = matrix.
// ---------------------------------------------------------------------------
__global__ __launch_bounds__(256) void wconv_kernel(const float* __restrict__ src,
                                                    ushort_t* __restrict__ dst,
                                                    int K, int N)
{
    __shared__ float tile[32][33];
    size_t moff = (size_t)blockIdx.z * K * N;
    src += moff; dst += moff;
    int n0 = blockIdx.x * 32, k0 = blockIdx.y * 32;
    int tx = threadIdx.x & 31, ty = threadIdx.x >> 5;
    #pragma unroll
    for (int i = 0; i < 4; ++i)
        tile[ty + i*8][tx] = src[(size_t)(k0 + ty + i*8) * N + n0 + tx];
    __syncthreads();
    #pragma unroll
    for (int i = 0; i < 4; ++i)
        dst[(size_t)(n0 + ty + i*8) * K + k0 + tx] = f2bf(tile[tx][ty + i*8]);
}

// ---------------------------------------------------------------------------
// Embedding / broadcast / LN / pred
// ---------------------------------------------------------------------------
__global__ void embed_kernel(const float* __restrict__ x, const float* __restrict__ pe,
                             const float* __restrict__ ew, const float* __restrict__ eb,
                             float* __restrict__ hf, ushort_t* __restrict__ hb)
{
    size_t row = blockIdx.x;
    int c = threadIdx.x;
    int l = (int)(row % L_);
    float x0 = x[row*2], x1 = x[row*2+1];
    float v0 = fmaf(x0, ew[c], fmaf(x1, ew[256 + c], eb[c]));
    float v1 = pe[(size_t)l*256 + c];
    hf[row*(size_t)D_ + c]       = v0;
    hf[row*(size_t)D_ + 256 + c] = v1;
    hb[row*(size_t)D_ + c]       = f2bf(v0);
    hb[row*(size_t)D_ + 256 + c] = f2bf(v1);
}

__global__ void bcast_kernel(const float* __restrict__ src,
                             float* __restrict__ dstf, ushort_t* __restrict__ dstb)
{
    size_t i = (size_t)blockIdx.x * 256 + threadIdx.x;
    float v = src[i];
    ushort_t bb16 = f2bf(v);
    #pragma unroll
    for (int bb = 0; bb < B_; ++bb) {
        dstf[(size_t)bb * L_ * D_ + i] = v;
        dstb[(size_t)bb * L_ * D_ + i] = bb16;
    }
}

__global__ __launch_bounds__(256) void ln_kernel(const float* __restrict__ X,
                                                 const float* __restrict__ gb,
                                                 float* __restrict__ Yf,
                                                 ushort_t* __restrict__ Yb)
{
    int row = blockIdx.x * 4 + (threadIdx.x >> 6);
    int lane = threadIdx.x & 63;
    const float* x = X + (size_t)row * D_;
    float v[8];
    float s = 0.f;
    #pragma unroll
    for (int i = 0; i < 8; ++i) { v[i] = x[lane + i*64]; s += v[i]; }
    #pragma unroll
    for (int off = 32; off >= 1; off >>= 1) s += __shfl_xor(s, off, 64);
    float mu = s * (1.f / D_);
    float sq = 0.f;
    #pragma unroll
    for (int i = 0; i < 8; ++i) { float d = v[i] - mu; sq += d * d; }
    #pragma unroll
    for (int off = 32; off >= 1; off >>= 1) sq += __shfl_xor(sq, off, 64);
    float rstd = rsqrtf(sq * (1.f / D_) + EPS_LN);
    #pragma unroll
    for (int i = 0; i < 8; ++i) {
        int c = lane + i*64;
        float y = (v[i] - mu) * rstd * gb[c] + gb[512 + c];
        Yf[(size_t)row * D_ + c] = y;
        if (Yb) Yb[(size_t)row * D_ + c] = f2bf(y);
    }
}

__global__ __launch_bounds__(256) void pred_kernel(const float* __restrict__ X,
                                                   const float* __restrict__ pw,
                                                   const float* __restrict__ pb,
                                                   float* __restrict__ out)
{
    int row = blockIdx.x * 4 + (threadIdx.x >> 6);
    int lane = threadIdx.x & 63;
    const float* x = X + (size_t)row * D_;
    float a0 = 0.f, a1 = 0.f;
    #pragma unroll
    for (int i = 0; i < 8; ++i) {
        int c = lane + i*64;
        float v = x[c];
        a0 = fmaf(v, pw[c*2 + 0], a0);
        a1 = fmaf(v, pw[c*2 + 1], a1);
    }
    #pragma unroll
    for (int off = 32; off >= 1; off >>= 1) {
        a0 += __shfl_xor(a0, off, 64);
        a1 += __shfl_xor(a1, off, 64);
    }
    if (lane == 0) {
        out[(size_t)row*2 + 0] = a0 + pb[0];
        out[(size_t)row*2 + 1] = a1 + pb[1];
    }
}

// ---------------------------------------------------------------------------
// Host-side orchestration
// ---------------------------------------------------------------------------
extern "C" void kernel_launch(void* const* d_in, const int* in_sizes, int n_in,
                              void* d_out, int out_size, void* d_ws, size_t ws_size,
                              hipStream_t stream)
{
    const float* x            = (const float*)d_in[0];
    const float* out_pos_emb  = (const float*)d_in[1];
    const float* pe_input     = (const float*)d_in[2];
    const float* emb_w        = (const float*)d_in[3];
    const float* emb_b        = (const float*)d_in[4];
    const float* enc_attn_w   = (const float*)d_in[5];
    const float* enc_attn_b   = (const float*)d_in[6];
    const float* enc_ln       = (const float*)d_in[7];
    const float* enc_ff_w1    = (const float*)d_in[8];
    const float* enc_ff_b1    = (const float*)d_in[9];
    const float* enc_ff_w2    = (const float*)d_in[10];
    const float* enc_ff_b2    = (const float*)d_in[11];
    const float* enc_final_ln = (const float*)d_in[12];
    const float* dec_self_w   = (const float*)d_in[13];
    const float* dec_self_b   = (const float*)d_in[14];
    const float* dec_cross_w  = (const float*)d_in[15];
    const float* dec_cross_b  = (const float*)d_in[16];
    const float* dec_ln       = (const float*)d_in[17];
    const float* dec_ff_w1    = (const float*)d_in[18];
    const float* dec_ff_b1    = (const float*)d_in[19];
    const float* dec_ff_w2    = (const float*)d_in[20];
    const float* dec_ff_b2    = (const float*)d_in[21];
    const float* dec_final_ln = (const float*)d_in[22];
    const float* pred_w       = (const float*)d_in[23];
    const float* pred_b       = (const float*)d_in[24];
    float* out = (float*)d_out;

    // ---- workspace layout (~198 MB) ----
    const size_t MD = (size_t)M_ * D_;            // 8.39M
    float*    h_f32 = (float*)d_ws;               // MD f32 (residual state, in-place)
    ushort_t* h_b   = (ushort_t*)(h_f32 + MD);    // MD bf16
    ushort_t* z_b   = h_b + MD;                   // MD bf16
    ushort_t* un    = z_b + MD;                   // union region
    // attn view of union:
    ushort_t* Qb = un;                            // MD
    ushort_t* ab = un + MD;                       // MD
    ushort_t* Kt = un + 2*MD;                     // 32*64*4096 = MD
    ushort_t* Vt = un + 3*MD;                     // 32*64*4096 = MD
    // ffn view of union:
    ushort_t* ffh = un;                           // M*F = 4*MD
    const size_t UN_ELEMS = 4*MD;
    ushort_t* kvb = un + UN_ELEMS;                // 32*80*64 bf16
    float*    kvp = (float*)(kvb + (size_t)32*80*64);   // 8*32*80*64 fp32 (5.2MB)
    ushort_t* wts = (ushort_t*)(kvp + (size_t)8*32*80*64);

    const size_t ATT_MAT = (size_t)D_ * D_;
    const size_t ATT_LYR = 4 * ATT_MAT;
    const size_t FF_MAT  = (size_t)D_ * F_;
    ushort_t* wt_enc_att   = wts;
    ushort_t* wt_dec_self  = wt_enc_att  + 4 * ATT_LYR;
    ushort_t* wt_dec_cross = wt_dec_self + 4 * ATT_LYR;
    ushort_t* wt_enc_ff1   = wt_dec_cross + 4 * ATT_LYR;
    ushort_t* wt_enc_ff2   = wt_enc_ff1  + 4 * FF_MAT;
    ushort_t* wt_dec_ff1   = wt_enc_ff2  + 4 * FF_MAT;
    ushort_t* wt_dec_ff2   = wt_dec_ff1  + 4 * FF_MAT;

    // ---- weight conversion (fp32 [K,N] -> bf16 [N,K]) ----
    hipLaunchKernelGGL(wconv_kernel, dim3(16, 16, 16), dim3(256), 0, stream,
                       enc_attn_w, wt_enc_att, D_, D_);
    hipLaunchKernelGGL(wconv_kernel, dim3(16, 16, 16), dim3(256), 0, stream,
                       dec_self_w, wt_dec_self, D_, D_);
    hipLaunchKernelGGL(wconv_kernel, dim3(16, 16, 16), dim3(256), 0, stream,
                       dec_cross_w, wt_dec_cross, D_, D_);
    hipLaunchKernelGGL(wconv_kernel, dim3(64, 16, 4), dim3(256), 0, stream,
                       enc_ff_w1, wt_enc_ff1, D_, F_);
    hipLaunchKernelGGL(wconv_kernel, dim3(16, 64, 4), dim3(256), 0, stream,
                       enc_ff_w2, wt_enc_ff2, F_, D_);
    hipLaunchKernelGGL(wconv_kernel, dim3(64, 16, 4), dim3(256), 0, stream,
                       dec_ff_w1, wt_dec_ff1, D_, F_);
    hipLaunchKernelGGL(wconv_kernel, dim3(16, 64, 4), dim3(256), 0, stream,
                       dec_ff_w2, wt_dec_ff2, F_, D_);

    auto gemm = [&](const ushort_t* A, const ushort_t* Wt, const float* bias,
                    const float* resid, float* Cf, ushort_t* Cb, int N, int K, int epi) {
        dim3 grid(N / 128, M_ / 128);
        hipLaunchKernelGGL(mfma_gemm, grid, dim3(512), 0, stream,
                           A, Wt, bias, resid, Cf, Cb, N, K, epi);
    };
    auto layernorm = [&](const float* gb, ushort_t* Yb) {   // in-place on h_f32
        hipLaunchKernelGGL(ln_kernel, dim3(M_ / 4), dim3(256), 0, stream,
                           h_f32, gb, h_f32, Yb);
    };
    // attention: h_f32 += proj(linear_attn(phi(xq Wq), phi(xkv Wk), xkv Wv))
    auto attn = [&](const ushort_t* xq_b, const ushort_t* xkv_b, bool self,
                    const ushort_t* wt, const float* bv) {
        if (self) {
            // fused Q|K|V projection, N = 1536
            hipLaunchKernelGGL(gemm_kv, dim3(12, 128), dim3(512), 0, stream,
                               xkv_b, wt, bv, 512, Qb, Kt, Vt);
        } else {
            gemm(xq_b, wt, bv, nullptr, nullptr, Qb, D_, D_, EPI_PHI);
            hipLaunchKernelGGL(gemm_kv, dim3(8, 128), dim3(512), 0, stream,
                               xkv_b, wt + ATT_MAT, bv + D_, 0, nullptr, Kt, Vt);
        }
        hipLaunchKernelGGL(kv_mfma, dim3(32, 8), dim3(256), 0, stream, Kt, Vt, kvp);
        hipLaunchKernelGGL(kv_reduce, dim3(32*80*64/256), dim3(256), 0, stream,
                           kvp, kvb);
        hipLaunchKernelGGL(attn_out_mfma, dim3(32, 32), dim3(256), 0, stream,
                           Qb, kvb, ab);
        gemm(ab, wt + 3*ATT_MAT, bv + 3*D_, h_f32, h_f32, nullptr, D_, D_, EPI_NONE);
    };
    auto ffn = [&](const ushort_t* wt1, const float* b1,
                   const ushort_t* wt2, const float* b2) {
        gemm(h_b, wt1, b1, nullptr, nullptr, ffh, F_, D_, EPI_RELU);
        gemm(ffh, wt2, b2, h_f32, h_f32, nullptr, D_, F_, EPI_NONE);
    };

    // ---- embedding ----
    hipLaunchKernelGGL(embed_kernel, dim3(M_), dim3(256), 0, stream,
                       x, pe_input, emb_w, emb_b, h_f32, h_b);

    // ---- encoder ----
    for (int l = 0; l < NLAYERS; ++l) {
        attn(h_b, h_b, true, wt_enc_att + l * ATT_LYR, enc_attn_b + (size_t)l * 4 * D_);
        layernorm(enc_ln + (size_t)(l*2 + 0) * 2 * D_, h_b);
        ffn(wt_enc_ff1 + l * FF_MAT, enc_ff_b1 + (size_t)l * F_,
            wt_enc_ff2 + l * FF_MAT, enc_ff_b2 + (size_t)l * D_);
        layernorm(enc_ln + (size_t)(l*2 + 1) * 2 * D_, h_b);
    }
    layernorm(enc_final_ln, z_b);    // z (bf16) = encoder memory

    // ---- decoder ----
    hipLaunchKernelGGL(bcast_kernel, dim3(L_ * D_ / 256), dim3(256), 0, stream,
                       out_pos_emb, h_f32, h_b);
    for (int l = 0; l < NLAYERS; ++l) {
        attn(h_b, h_b, true, wt_dec_self + l * ATT_LYR, dec_self_b + (size_t)l * 4 * D_);
        layernorm(dec_ln + (size_t)(l*3 + 0) * 2 * D_, h_b);
        attn(h_b, z_b, false, wt_dec_cross + l * ATT_LYR, dec_cross_b + (size_t)l * 4 * D_);
        layernorm(dec_ln + (size_t)(l*3 + 1) * 2 * D_, h_b);
        ffn(wt_dec_ff1 + l * FF_MAT, dec_ff_b1 + (size_t)l * F_,
            wt_dec_ff2 + l * FF_MAT, dec_ff_b2 + (size_t)l * D_);
        layernorm(dec_ln + (size_t)(l*3 + 2) * 2 * D_, h_b);
    }
    layernorm(dec_final_ln, nullptr);   // in-place on h_f32

    // ---- prediction head ----
    hipLaunchKernelGGL(pred_kernel, dim3(M_ / 4), dim3(256), 0, stream,
                       h_f32, pred_w, pred_b, out);
}